// Round 1
// baseline (124.810 us; speedup 1.0000x reference)
//
#include <hip/hip_runtime.h>
#include <hip/hip_bf16.h>

typedef __attribute__((ext_vector_type(8))) short bf16x8;
typedef __attribute__((ext_vector_type(4))) float f32x4;

#define LOG2E 1.4426950408889634f

__device__ __forceinline__ ushort f2bf(float f) {
    // round-to-nearest-even f32 -> bf16 (inputs are finite, no NaN handling)
    uint u = __float_as_uint(f);
    u += 0x7FFFu + ((u >> 16) & 1u);
    return (ushort)(u >> 16);
}

__global__ __launch_bounds__(256, 4)
void attn_fused(const float* __restrict__ full,
                const float* __restrict__ last,
                const float* __restrict__ W1w, const float* __restrict__ W1b,
                const float* __restrict__ W2w, const float* __restrict__ W2b,
                const float* __restrict__ Vw,  const float* __restrict__ Vb,
                float* __restrict__ out, int T)
{
    __shared__ ushort w2bf[64][64];     // bf16 bits of W2 [o][d]
    __shared__ float qpart[4][64];
    __shared__ float qt[64];            // q~ = W1b + W2b + last @ W1^T
    __shared__ float vsh[64];
    __shared__ float accbuf[4][64];
    __shared__ float mbuf[4];
    __shared__ float lbuf[4];

    const int b    = blockIdx.x;
    const int tid  = threadIdx.x;
    const int lane = tid & 63;
    const int wv   = tid >> 6;          // wave 0..3

    // ---------------- stage 0: q~, W2->bf16, V ----------------
    {
        int o = tid & 63, pg = tid >> 6;
        const float* lrow = last + (size_t)b * 64 + pg * 16;
        const float* wrow = W1w + (size_t)o * 64 + pg * 16;
        float s = 0.f;
        #pragma unroll
        for (int j = 0; j < 16; ++j) s = fmaf(lrow[j], wrow[j], s);
        qpart[pg][o] = s;

        int base = tid * 16;
        #pragma unroll
        for (int j = 0; j < 16; j += 4) {
            float4 w4 = *reinterpret_cast<const float4*>(W2w + base + j);
            ushort* dst = &w2bf[0][0] + base + j;
            dst[0] = f2bf(w4.x); dst[1] = f2bf(w4.y);
            dst[2] = f2bf(w4.z); dst[3] = f2bf(w4.w);
        }
        if (tid < 64) vsh[tid] = Vw[tid];
    }
    __syncthreads();
    if (tid < 64)
        qt[tid] = W1b[tid] + W2b[tid] + qpart[0][tid] + qpart[1][tid]
                + qpart[2][tid] + qpart[3][tid];
    __syncthreads();

    // ---------------- per-lane MFMA constants ----------------
    const int col  = lane & 15;   // row index (A) / col index (B,D) within 16-tile
    const int grp  = lane >> 4;   // k-group
    const int koff = grp * 8;

    // B fragments: B[k=d, c=o] = W2^T  -> lane holds W2[ot*16+col][kc*32+koff .. +7]
    bf16x8 bfr[4][2];
    #pragma unroll
    for (int ot = 0; ot < 4; ++ot)
        #pragma unroll
        for (int kc = 0; kc < 2; ++kc)
            bfr[ot][kc] = *reinterpret_cast<const bf16x8*>(
                              &w2bf[ot * 16 + col][kc * 32 + koff]);

    float q4[4], v4[4];
    #pragma unroll
    for (int ot = 0; ot < 4; ++ot) {
        q4[ot] = qt[ot * 16 + col];
        v4[ot] = vsh[ot * 16 + col];
    }
    const float vb0 = Vb[0];

    const int ntile = T / (4 * 16);           // tiles per wave (T=2048 -> 32)
    const size_t browbase = (size_t)b * T;

    float m = -1e30f, l = 0.f, acc = 0.f;     // acc: lane owns d = lane

    for (int it = 0; it < ntile; ++it) {
        const int t0 = (wv * ntile + it) * 16;

        // A-operand loads: row = t0+col, 8 consecutive d per k-chunk
        const float* xr = full + (browbase + t0 + col) * 64;
        float4 a00 = *reinterpret_cast<const float4*>(xr + koff);
        float4 a01 = *reinterpret_cast<const float4*>(xr + koff + 4);
        float4 a10 = *reinterpret_cast<const float4*>(xr + 32 + koff);
        float4 a11 = *reinterpret_cast<const float4*>(xr + 32 + koff + 4);

        // PV column loads (coalesced, L1-hot): lane = d, 16 rows
        float xc[16];
        #pragma unroll
        for (int t = 0; t < 16; ++t)
            xc[t] = full[(browbase + t0 + t) * 64 + lane];

        bf16x8 af0, af1;
        af0[0]=f2bf(a00.x); af0[1]=f2bf(a00.y); af0[2]=f2bf(a00.z); af0[3]=f2bf(a00.w);
        af0[4]=f2bf(a01.x); af0[5]=f2bf(a01.y); af0[6]=f2bf(a01.z); af0[7]=f2bf(a01.w);
        af1[0]=f2bf(a10.x); af1[1]=f2bf(a10.y); af1[2]=f2bf(a10.z); af1[3]=f2bf(a10.w);
        af1[4]=f2bf(a11.x); af1[5]=f2bf(a11.y); af1[6]=f2bf(a11.z); af1[7]=f2bf(a11.w);

        // scores: k = x @ W2^T (per 16-o tile), h = tanh(q~ + k), hv += h*V[o]
        float hv[4] = {0.f, 0.f, 0.f, 0.f};
        #pragma unroll
        for (int ot = 0; ot < 4; ++ot) {
            f32x4 dd = {0.f, 0.f, 0.f, 0.f};
            dd = __builtin_amdgcn_mfma_f32_16x16x32_bf16(af0, bfr[ot][0], dd, 0, 0, 0);
            dd = __builtin_amdgcn_mfma_f32_16x16x32_bf16(af1, bfr[ot][1], dd, 0, 0, 0);
            #pragma unroll
            for (int r = 0; r < 4; ++r) {
                float pre = dd[r] + q4[ot];
                // tanh(x) = 1 - 2/(exp2(2x*log2e)+1)
                float e = exp2f(pre * (2.f * LOG2E));
                float h = fmaf(-2.f, __builtin_amdgcn_rcpf(e + 1.f), 1.f);
                hv[r] = fmaf(h, v4[ot], hv[r]);
            }
        }

        // sum over o (16 cols spread over lane bits 0..3)
        #pragma unroll
        for (int msk = 1; msk <= 8; msk <<= 1)
            #pragma unroll
            for (int r = 0; r < 4; ++r)
                hv[r] += __shfl_xor(hv[r], msk);

        float s4[4];
        #pragma unroll
        for (int r = 0; r < 4; ++r) s4[r] = hv[r] + vb0;  // score(t = t0 + grp*4 + r)

        // tile max across all 16 t's
        float tm = fmaxf(fmaxf(s4[0], s4[1]), fmaxf(s4[2], s4[3]));
        #pragma unroll
        for (int msk = 1; msk <= 32; msk <<= 1)
            tm = fmaxf(tm, __shfl_xor(tm, msk));

        float mnew  = fmaxf(m, tm);
        float scale = exp2f((m - mnew) * LOG2E);
        acc *= scale;
        l   *= scale;
        m    = mnew;

        float p4[4];
        #pragma unroll
        for (int r = 0; r < 4; ++r) p4[r] = exp2f((s4[r] - mnew) * LOG2E);

        // PV: acc[d=lane] += p_t * x[t,d]; p_t broadcast from lane 16*(t>>2), reg t&3
        #pragma unroll
        for (int t = 0; t < 16; ++t) {
            float pt = __uint_as_float(
                __builtin_amdgcn_readlane(__float_as_uint(p4[t & 3]), (t >> 2) * 16));
            l   += pt;
            acc  = fmaf(pt, xc[t], acc);
        }
    }

    // ---------------- cross-wave combine ----------------
    if (lane == 0) { mbuf[wv] = m; lbuf[wv] = l; }
    accbuf[wv][lane] = acc;
    __syncthreads();

    if (tid < 64) {
        float mstar = fmaxf(fmaxf(mbuf[0], mbuf[1]), fmaxf(mbuf[2], mbuf[3]));
        float L = 0.f, a = 0.f;
        #pragma unroll
        for (int w = 0; w < 4; ++w) {
            float sc = exp2f((mbuf[w] - mstar) * LOG2E);
            L += lbuf[w] * sc;
            a  = fmaf(accbuf[w][tid], sc, a);
        }
        out[(size_t)b * 64 + tid] = a / L;
    }
}

extern "C" void kernel_launch(void* const* d_in, const int* in_sizes, int n_in,
                              void* d_out, int out_size, void* d_ws, size_t ws_size,
                              hipStream_t stream) {
    const float* full = (const float*)d_in[0];
    const float* last = (const float*)d_in[1];
    const float* W1w  = (const float*)d_in[2];
    const float* W1b  = (const float*)d_in[3];
    const float* W2w  = (const float*)d_in[4];
    const float* W2b  = (const float*)d_in[5];
    const float* Vw   = (const float*)d_in[6];
    const float* Vb   = (const float*)d_in[7];
    float* out = (float*)d_out;

    const int Bn = in_sizes[1] / 64;              // 1024
    const int T  = in_sizes[0] / in_sizes[1];     // 2048

    attn_fused<<<Bn, 256, 0, stream>>>(full, last, W1w, W1b, W2w, W2b, Vw, Vb, out, T);
}

// Round 2
// 121.025 us; speedup vs baseline: 1.0313x; 1.0313x over previous
//
#include <hip/hip_runtime.h>
#include <hip/hip_bf16.h>

typedef __attribute__((ext_vector_type(8))) short bf16x8;
typedef __attribute__((ext_vector_type(4))) float f32x4;

#define LOG2E 1.4426950408889634f

__device__ __forceinline__ ushort f2bf(float f) {
    // RNE f32->bf16 via header cast; compiler fuses pairs into v_cvt_pk_bf16_f32
    return __builtin_bit_cast(ushort, __float2bfloat16(f));
}

struct TileRegs { f32x4 a00, a01, a10, a11; };

__device__ __forceinline__ void load_tile(TileRegs& t, const float* xr) {
    t.a00 = *reinterpret_cast<const f32x4*>(xr);
    t.a01 = *reinterpret_cast<const f32x4*>(xr + 4);
    t.a10 = *reinterpret_cast<const f32x4*>(xr + 32);
    t.a11 = *reinterpret_cast<const f32x4*>(xr + 36);
}

__global__ __launch_bounds__(256, 4)
void attn_fused(const float* __restrict__ full,
                const float* __restrict__ last,
                const float* __restrict__ W1w, const float* __restrict__ W1b,
                const float* __restrict__ W2w, const float* __restrict__ W2b,
                const float* __restrict__ Vw,  const float* __restrict__ Vb,
                float* __restrict__ out, int T)
{
    __shared__ ushort w2bf[64][64];     // bf16 bits of W2 [o][d]
    __shared__ float qpart[4][64];
    __shared__ float qt[64];            // q~ = W1b + W2b + last @ W1^T
    __shared__ float vsh[64];
    __shared__ float accbuf[4][64];
    __shared__ float lbuf[4];

    const int b    = blockIdx.x;
    const int tid  = threadIdx.x;
    const int lane = tid & 63;
    const int wv   = tid >> 6;          // wave 0..3

    // ---------------- stage 0: q~, W2->bf16, V ----------------
    {
        int o = tid & 63, pg = tid >> 6;
        const float4* lr = reinterpret_cast<const float4*>(last + (size_t)b * 64 + pg * 16);
        const float4* wr = reinterpret_cast<const float4*>(W1w + (size_t)o * 64 + pg * 16);
        float s = 0.f;
        #pragma unroll
        for (int j = 0; j < 4; ++j) {
            float4 a = lr[j], w = wr[j];
            s = fmaf(a.x, w.x, s); s = fmaf(a.y, w.y, s);
            s = fmaf(a.z, w.z, s); s = fmaf(a.w, w.w, s);
        }
        qpart[pg][o] = s;

        int base = tid * 16;
        #pragma unroll
        for (int j = 0; j < 16; j += 4) {
            float4 w4 = *reinterpret_cast<const float4*>(W2w + base + j);
            ushort* dst = &w2bf[0][0] + base + j;
            dst[0] = f2bf(w4.x); dst[1] = f2bf(w4.y);
            dst[2] = f2bf(w4.z); dst[3] = f2bf(w4.w);
        }
        if (tid < 64) vsh[tid] = Vw[tid];
    }
    __syncthreads();
    if (tid < 64)
        qt[tid] = W1b[tid] + W2b[tid] + qpart[0][tid] + qpart[1][tid]
                + qpart[2][tid] + qpart[3][tid];
    __syncthreads();

    // ---------------- per-lane MFMA constants ----------------
    const int col  = lane & 15;   // A-row (t) index / B,D col (o) index
    const int grp  = lane >> 4;   // k-group
    const int koff = grp * 8;

    // B fragments: B[k=d, c=o] = W2^T  -> lane holds W2[ot*16+col][kc*32+koff .. +7]
    bf16x8 bfr[4][2];
    #pragma unroll
    for (int ot = 0; ot < 4; ++ot)
        #pragma unroll
        for (int kc = 0; kc < 2; ++kc)
            bfr[ot][kc] = *reinterpret_cast<const bf16x8*>(
                              &w2bf[ot * 16 + col][kc * 32 + koff]);

    // per-col folded constants
    float q2[4], vm2[4], sv = 0.f;
    #pragma unroll
    for (int ot = 0; ot < 4; ++ot) {
        float v = vsh[ot * 16 + col];
        vm2[ot] = -2.f * v;
        sv += v;
        q2[ot] = qt[ot * 16 + col] * (2.f * LOG2E);
    }
    const float vbl = Vb[0] * LOG2E;

    const int ntile = T / (4 * 16);           // tiles per wave (T=2048 -> 32)
    const size_t rowbase = ((size_t)blockIdx.x * T + (size_t)wv * ntile * 16 + col) * 64 + koff;
    const float* xbase = full + rowbase;      // advances 16*64 floats per tile

    float acc16[16];
    #pragma unroll
    for (int i = 0; i < 16; ++i) acc16[i] = 0.f;
    float l = 0.f;

    const int lastIt = ntile - 1;

    TileRegs A, B;
    load_tile(A, xbase);

    // compute one 16-row tile held in regs `t`
    auto compute = [&](const TileRegs& t) {
        bf16x8 af0, af1;
        af0[0]=f2bf(t.a00[0]); af0[1]=f2bf(t.a00[1]); af0[2]=f2bf(t.a00[2]); af0[3]=f2bf(t.a00[3]);
        af0[4]=f2bf(t.a01[0]); af0[5]=f2bf(t.a01[1]); af0[6]=f2bf(t.a01[2]); af0[7]=f2bf(t.a01[3]);
        af1[0]=f2bf(t.a10[0]); af1[1]=f2bf(t.a10[1]); af1[2]=f2bf(t.a10[2]); af1[3]=f2bf(t.a10[3]);
        af1[4]=f2bf(t.a11[0]); af1[5]=f2bf(t.a11[1]); af1[6]=f2bf(t.a11[2]); af1[7]=f2bf(t.a11[3]);

        // hv[r] = sum_o V[o]*tanh(q_o + k[t,o]),  t = t0 + grp*4 + r  (pre-reduction)
        float hv[4] = {sv, sv, sv, sv};
        #pragma unroll
        for (int ot = 0; ot < 4; ++ot) {
            f32x4 dd = {0.f, 0.f, 0.f, 0.f};
            dd = __builtin_amdgcn_mfma_f32_16x16x32_bf16(af0, bfr[ot][0], dd, 0, 0, 0);
            dd = __builtin_amdgcn_mfma_f32_16x16x32_bf16(af1, bfr[ot][1], dd, 0, 0, 0);
            #pragma unroll
            for (int r = 0; r < 4; ++r) {
                // tanh(x) = 1 - 2/(exp2(2x*log2e)+1); the "+1*v" is folded into sv
                float e  = exp2f(fmaf(dd[r], 2.f * LOG2E, q2[ot]));
                float rc = __builtin_amdgcn_rcpf(e + 1.f);
                hv[r] = fmaf(vm2[ot], rc, hv[r]);
            }
        }

        // reduce over the 16 o-cols (lane bits 0..3)
        #pragma unroll
        for (int msk = 1; msk <= 8; msk <<= 1)
            #pragma unroll
            for (int r = 0; r < 4; ++r)
                hv[r] += __shfl_xor(hv[r], msk);

        // p = exp(score), fixed m=0 (scores bounded ~|Sigma|V||+|Vb| < 10)
        float p4[4];
        #pragma unroll
        for (int r = 0; r < 4; ++r)
            p4[r] = exp2f(fmaf(hv[r], LOG2E, vbl));

        l += (p4[0] + p4[1]) + (p4[2] + p4[3]);

        // p for t = t0 + col: from lane group (col>>2), reg (col&3)
        int srcl = (col >> 2) * 16;
        float c0 = __shfl(p4[0], srcl);
        float c1 = __shfl(p4[1], srcl);
        float c2 = __shfl(p4[2], srcl);
        float c3 = __shfl(p4[3], srcl);
        float pa   = (col & 1) ? c1 : c0;
        float pb   = (col & 1) ? c3 : c2;
        float pcol = (col & 2) ? pb : pa;

        // PV: reuse the f32 tile regs; lane owns d = {grp*8+j, 32+grp*8+j}
        #pragma unroll
        for (int j = 0; j < 4; ++j) {
            acc16[j]      = fmaf(pcol, t.a00[j], acc16[j]);
            acc16[4 + j]  = fmaf(pcol, t.a01[j], acc16[4 + j]);
            acc16[8 + j]  = fmaf(pcol, t.a10[j], acc16[8 + j]);
            acc16[12 + j] = fmaf(pcol, t.a11[j], acc16[12 + j]);
        }
    };

    // ping-pong 2-deep pipeline (ntile is even)
    for (int it = 0; it < ntile; it += 2) {
        load_tile(B, xbase + (size_t)(it + 1) * 1024);
        compute(A);
        int nx = (it + 2 <= lastIt) ? (it + 2) : lastIt;   // last prefetch clamped (unused)
        load_tile(A, xbase + (size_t)nx * 1024);
        compute(B);
    }

    // ---------------- end reductions ----------------
    #pragma unroll
    for (int msk = 1; msk <= 8; msk <<= 1)
        #pragma unroll
        for (int i = 0; i < 16; ++i)
            acc16[i] += __shfl_xor(acc16[i], msk);

    l += __shfl_xor(l, 16);
    l += __shfl_xor(l, 32);

    if (col == 0) {
        #pragma unroll
        for (int j = 0; j < 8; ++j) {
            accbuf[wv][grp * 8 + j]      = acc16[j];
            accbuf[wv][32 + grp * 8 + j] = acc16[8 + j];
        }
    }
    if (lane == 0) lbuf[wv] = l;
    __syncthreads();

    if (tid < 64) {
        float L = (lbuf[0] + lbuf[1]) + (lbuf[2] + lbuf[3]);
        float a = (accbuf[0][tid] + accbuf[1][tid])
                + (accbuf[2][tid] + accbuf[3][tid]);
        out[(size_t)blockIdx.x * 64 + tid] = a / L;
    }
}

extern "C" void kernel_launch(void* const* d_in, const int* in_sizes, int n_in,
                              void* d_out, int out_size, void* d_ws, size_t ws_size,
                              hipStream_t stream) {
    const float* full = (const float*)d_in[0];
    const float* last = (const float*)d_in[1];
    const float* W1w  = (const float*)d_in[2];
    const float* W1b  = (const float*)d_in[3];
    const float* W2w  = (const float*)d_in[4];
    const float* W2b  = (const float*)d_in[5];
    const float* Vw   = (const float*)d_in[6];
    const float* Vb   = (const float*)d_in[7];
    float* out = (float*)d_out;

    const int Bn = in_sizes[1] / 64;              // 1024
    const int T  = in_sizes[0] / in_sizes[1];     // 2048

    attn_fused<<<Bn, 256, 0, stream>>>(full, last, W1w, W1b, W2w, W2b, Vw, Vb, out, T);
}

// Round 3
// 120.403 us; speedup vs baseline: 1.0366x; 1.0052x over previous
//
#include <hip/hip_runtime.h>
#include <hip/hip_bf16.h>

typedef __attribute__((ext_vector_type(8))) short bf16x8;
typedef __attribute__((ext_vector_type(4))) float f32x4;

#define LOG2E 1.4426950408889634f

__device__ __forceinline__ ushort f2bf(float f) {
    return __builtin_bit_cast(ushort, __float2bfloat16(f));
}

typedef __attribute__((address_space(1))) const void gvoid;
typedef __attribute__((address_space(3))) void lvoid;

__global__ __launch_bounds__(256, 4)
void attn_fused(const float* __restrict__ full,
                const float* __restrict__ last,
                const float* __restrict__ W1w, const float* __restrict__ W1b,
                const float* __restrict__ W2w, const float* __restrict__ W2b,
                const float* __restrict__ Vw,  const float* __restrict__ Vb,
                float* __restrict__ out, int T)
{
    // per-wave private double-buffered staging: [wave][ring][16 rows * 64 f32]
    __shared__ __align__(16) float sbuf[4][2][1024];
    __shared__ float qpart[4][64];
    __shared__ float qt[64];
    __shared__ float vsh[64];
    __shared__ float accbuf[4][64];
    __shared__ float lbuf[4];

    const int tid  = threadIdx.x;
    const int lane = tid & 63;
    const int wv   = tid >> 6;
    const int col  = lane & 15;   // MFMA A-row / B,D col
    const int grp  = lane >> 4;   // k-group

    // ---------------- stage 0: q~ partials, V ----------------
    {
        int o = tid & 63, pg = tid >> 6;
        const float4* lr = reinterpret_cast<const float4*>(last + (size_t)blockIdx.x * 64 + pg * 16);
        const float4* wr = reinterpret_cast<const float4*>(W1w + (size_t)o * 64 + pg * 16);
        float s = 0.f;
        #pragma unroll
        for (int j = 0; j < 4; ++j) {
            float4 a = lr[j], w = wr[j];
            s = fmaf(a.x, w.x, s); s = fmaf(a.y, w.y, s);
            s = fmaf(a.z, w.z, s); s = fmaf(a.w, w.w, s);
        }
        qpart[pg][o] = s;
        if (tid < 64) vsh[tid] = Vw[tid];
    }

    // B fragments direct from global: lane holds bf16 of W2[ot*16+col][kc*32+grp*8 ..+8]
    bf16x8 bfr[4][2];
    #pragma unroll
    for (int ot = 0; ot < 4; ++ot)
        #pragma unroll
        for (int kc = 0; kc < 2; ++kc) {
            const float* wp = W2w + (size_t)(ot * 16 + col) * 64 + kc * 32 + grp * 8;
            float4 w0 = *reinterpret_cast<const float4*>(wp);
            float4 w1 = *reinterpret_cast<const float4*>(wp + 4);
            bf16x8 f;
            f[0]=f2bf(w0.x); f[1]=f2bf(w0.y); f[2]=f2bf(w0.z); f[3]=f2bf(w0.w);
            f[4]=f2bf(w1.x); f[5]=f2bf(w1.y); f[6]=f2bf(w1.z); f[7]=f2bf(w1.w);
            bfr[ot][kc] = f;
        }

    __syncthreads();
    if (tid < 64)
        qt[tid] = W1b[tid] + W2b[tid] + qpart[0][tid] + qpart[1][tid]
                + qpart[2][tid] + qpart[3][tid];
    __syncthreads();

    float q2[4], vm2[4], sv = 0.f;
    #pragma unroll
    for (int ot = 0; ot < 4; ++ot) {
        float v = vsh[ot * 16 + col];
        vm2[ot] = -2.f * v;
        sv += v;
        q2[ot] = qt[ot * 16 + col] * (2.f * LOG2E);
    }
    const float vbl = Vb[0] * LOG2E;

    // ---------------- staging geometry ----------------
    // LDS layout: row r (0..15) of a tile holds its 16 16B-chunks permuted:
    // stored slot s <- global chunk q = s ^ (r & 15).  glds dest is lane-linear,
    // so source chunk for linear index ci = i*64+lane is (row=ci>>4, s=ci&15).
    int srcoff[4];    // float offsets into the tile for glds call i
    #pragma unroll
    for (int i = 0; i < 4; ++i) {
        int row = i * 4 + (lane >> 4);
        int q   = (lane & 15) ^ (row & 15);
        srcoff[i] = row * 64 + q * 4;
    }
    // ds_read byte offsets for the A fragments (chunk XOR row swizzle)
    const int offA0 = col * 256 + ((2 * grp)     ^ col) * 16;   // d in [g*8,   g*8+4)
    const int offA1 = col * 256 + ((2 * grp + 1) ^ col) * 16;   // d in [g*8+4, g*8+8)
    const int offA2 = col * 256 + ((8 + 2 * grp) ^ col) * 16;   // d in [32+g*8,    +4)
    const int offA3 = col * 256 + ((9 + 2 * grp) ^ col) * 16;   // d in [32+g*8+4,  +8)

    const int ntile = T / 64;                         // tiles per wave (32)
    const float* wbase = full + (size_t)blockIdx.x * T * 64 + (size_t)wv * ntile * 1024;
    char* lds0 = (char*)&sbuf[wv][0][0];
    char* lds1 = (char*)&sbuf[wv][1][0];

    auto stage = [&](char* lb, int t) {
        const float* tp = wbase + (size_t)t * 1024;
        #pragma unroll
        for (int i = 0; i < 4; ++i)
            __builtin_amdgcn_global_load_lds((gvoid*)(tp + srcoff[i]),
                                             (lvoid*)(lb + i * 1024), 16, 0, 0);
    };

    float acc16[16];
    #pragma unroll
    for (int i = 0; i < 16; ++i) acc16[i] = 0.f;
    float l = 0.f;

    // drain stage-0 loads so in-loop vmcnt counts only glds
    asm volatile("s_waitcnt vmcnt(0)" ::: "memory");
    stage(lds0, 0);
    stage(lds1, 1);

    for (int t = 0; t < ntile; ++t) {
        const char* lb = (t & 1) ? lds1 : lds0;
        if (t + 1 == ntile) asm volatile("s_waitcnt vmcnt(0)" ::: "memory");
        else                asm volatile("s_waitcnt vmcnt(4)" ::: "memory");
        __builtin_amdgcn_sched_barrier(0);

        f32x4 a00 = *reinterpret_cast<const f32x4*>(lb + offA0);
        f32x4 a01 = *reinterpret_cast<const f32x4*>(lb + offA1);
        f32x4 a10 = *reinterpret_cast<const f32x4*>(lb + offA2);
        f32x4 a11 = *reinterpret_cast<const f32x4*>(lb + offA3);

        asm volatile("s_waitcnt lgkmcnt(0)" ::: "memory");
        __builtin_amdgcn_sched_barrier(0);
        if (t + 2 < ntile) stage((char*)lb, t + 2);   // buffer free: reads retired

        // ---------------- compute (R2 body) ----------------
        bf16x8 af0, af1;
        af0[0]=f2bf(a00[0]); af0[1]=f2bf(a00[1]); af0[2]=f2bf(a00[2]); af0[3]=f2bf(a00[3]);
        af0[4]=f2bf(a01[0]); af0[5]=f2bf(a01[1]); af0[6]=f2bf(a01[2]); af0[7]=f2bf(a01[3]);
        af1[0]=f2bf(a10[0]); af1[1]=f2bf(a10[1]); af1[2]=f2bf(a10[2]); af1[3]=f2bf(a10[3]);
        af1[4]=f2bf(a11[0]); af1[5]=f2bf(a11[1]); af1[6]=f2bf(a11[2]); af1[7]=f2bf(a11[3]);

        float hv[4] = {sv, sv, sv, sv};
        #pragma unroll
        for (int ot = 0; ot < 4; ++ot) {
            f32x4 dd = {0.f, 0.f, 0.f, 0.f};
            dd = __builtin_amdgcn_mfma_f32_16x16x32_bf16(af0, bfr[ot][0], dd, 0, 0, 0);
            dd = __builtin_amdgcn_mfma_f32_16x16x32_bf16(af1, bfr[ot][1], dd, 0, 0, 0);
            #pragma unroll
            for (int r = 0; r < 4; ++r) {
                float e  = exp2f(fmaf(dd[r], 2.f * LOG2E, q2[ot]));
                float rc = __builtin_amdgcn_rcpf(e + 1.f);
                hv[r] = fmaf(vm2[ot], rc, hv[r]);
            }
        }

        #pragma unroll
        for (int msk = 1; msk <= 8; msk <<= 1)
            #pragma unroll
            for (int r = 0; r < 4; ++r)
                hv[r] += __shfl_xor(hv[r], msk);

        float p4[4];
        #pragma unroll
        for (int r = 0; r < 4; ++r)
            p4[r] = exp2f(fmaf(hv[r], LOG2E, vbl));

        l += (p4[0] + p4[1]) + (p4[2] + p4[3]);

        int srcl = (col >> 2) * 16;
        float c0 = __shfl(p4[0], srcl);
        float c1 = __shfl(p4[1], srcl);
        float c2 = __shfl(p4[2], srcl);
        float c3 = __shfl(p4[3], srcl);
        float pa   = (col & 1) ? c1 : c0;
        float pb   = (col & 1) ? c3 : c2;
        float pcol = (col & 2) ? pb : pa;

        #pragma unroll
        for (int j = 0; j < 4; ++j) {
            acc16[j]      = fmaf(pcol, a00[j], acc16[j]);
            acc16[4 + j]  = fmaf(pcol, a01[j], acc16[4 + j]);
            acc16[8 + j]  = fmaf(pcol, a10[j], acc16[8 + j]);
            acc16[12 + j] = fmaf(pcol, a11[j], acc16[12 + j]);
        }
    }

    // ---------------- end reductions (R2 verbatim) ----------------
    #pragma unroll
    for (int msk = 1; msk <= 8; msk <<= 1)
        #pragma unroll
        for (int i = 0; i < 16; ++i)
            acc16[i] += __shfl_xor(acc16[i], msk);

    l += __shfl_xor(l, 16);
    l += __shfl_xor(l, 32);

    if (col == 0) {
        #pragma unroll
        for (int j = 0; j < 8; ++j) {
            accbuf[wv][grp * 8 + j]      = acc16[j];
            accbuf[wv][32 + grp * 8 + j] = acc16[8 + j];
        }
    }
    if (lane == 0) lbuf[wv] = l;
    __syncthreads();

    if (tid < 64) {
        float L = (lbuf[0] + lbuf[1]) + (lbuf[2] + lbuf[3]);
        float a = (accbuf[0][tid] + accbuf[1][tid])
                + (accbuf[2][tid] + accbuf[3][tid]);
        out[(size_t)blockIdx.x * 64 + tid] = a / L;
    }
}

extern "C" void kernel_launch(void* const* d_in, const int* in_sizes, int n_in,
                              void* d_out, int out_size, void* d_ws, size_t ws_size,
                              hipStream_t stream) {
    const float* full = (const float*)d_in[0];
    const float* last = (const float*)d_in[1];
    const float* W1w  = (const float*)d_in[2];
    const float* W1b  = (const float*)d_in[3];
    const float* W2w  = (const float*)d_in[4];
    const float* W2b  = (const float*)d_in[5];
    const float* Vw   = (const float*)d_in[6];
    const float* Vb   = (const float*)d_in[7];
    float* out = (float*)d_out;

    const int Bn = in_sizes[1] / 64;              // 1024
    const int T  = in_sizes[0] / in_sizes[1];     // 2048

    attn_fused<<<Bn, 256, 0, stream>>>(full, last, W1w, W1b, W2w, W2b, Vw, Vb, out, T);
}